// Round 3
// baseline (1983.250 us; speedup 1.0000x reference)
//
#include <hip/hip_runtime.h>
#include <hip/hip_bf16.h>

typedef __hip_bfloat16 bf16;

__device__ __forceinline__ float b2f(bf16 v) { return __bfloat162float(v); }

// flags[0] = 1 if edge_index is int64, 0 if int32
// flags[1] = 1 if float tensors (and output) are fp32, 0 if bf16
__global__ void detect_kernel(const void* __restrict__ edge, const void* __restrict__ x,
                              int* __restrict__ flags) {
    if (blockIdx.x != 0 || threadIdx.x != 0) return;
    const int* e32 = (const int*)edge;
    int allzero = 1;
    // int64 little-endian: every odd int32 word is a high half == 0 (indices < 2^31).
    // Sample two regions; int32 data would need 1024 sampled values all == 0 (P ~ 0).
    for (int k = 1; k < 1024; k += 2)       if (e32[k] != 0) { allzero = 0; break; }
    if (allzero)
        for (int k = 1000001; k < 1002048; k += 2) if (e32[k] != 0) { allzero = 0; break; }
    flags[0] = allzero;
    // fp32 data misread as bf16: even slots = fp32 low mantissa bits -> random exponent field.
    const unsigned short* u = (const unsigned short*)x;
    int insane = 0;
    for (int k = 0; k < 512; k += 2) {
        int ex = (u[k] >> 7) & 0xFF;
        if (ex != 0 && (ex < 90 || ex > 160)) insane++;
    }
    flags[1] = (insane > 64) ? 1 : 0;
}

__device__ __forceinline__ int getIdx(const void* p, long long i, int is64) {
    return is64 ? (int)(((const long long*)p)[i]) : ((const int*)p)[i];
}
__device__ __forceinline__ float loadF(const void* p, size_t i, int isF32) {
    return isF32 ? ((const float*)p)[i] : b2f(((const bf16*)p)[i]);
}
__device__ __forceinline__ void storeF(void* p, size_t i, float v, int isF32) {
    if (isF32) ((float*)p)[i] = v;
    else       ((bf16*)p)[i]  = __float2bfloat16(v);
}

// ---------------- degree / dinv ----------------
__global__ void degree_kernel(const void* __restrict__ edge, long long dstOff, int E,
                              int* __restrict__ deg, const int* __restrict__ flags) {
    int e = blockIdx.x * blockDim.x + threadIdx.x;
    if (e < E) atomicAdd(&deg[getIdx(edge, dstOff + e, flags[0])], 1);
}

__global__ void dinv_kernel(const int* __restrict__ deg, float* __restrict__ dinv, int N) {
    int i = blockIdx.x * blockDim.x + threadIdx.x;
    if (i < N) dinv[i] = rsqrtf((float)deg[i] + 1.0f);
}

// ---------------- GEMM: out[N,64] = (relu?)in[N,64] @ W[64,64] ----------------
template <bool RELU, bool IN_IS_WS>
__global__ void gemm64_kernel(const void* __restrict__ in, const void* __restrict__ W,
                              float* __restrict__ out, int N, const int* __restrict__ flags) {
    __shared__ float Wl[64 * 64];
    const int isF32 = flags[1];
    for (int t = threadIdx.x; t < 64 * 64; t += blockDim.x) Wl[t] = loadF(W, t, isF32);
    __syncthreads();
    const int lane = threadIdx.x & 63;
    const int wpb  = blockDim.x >> 6;
    int row = blockIdx.x * wpb + (threadIdx.x >> 6);
    const int stride = gridDim.x * wpb;
    for (; row < N; row += stride) {
        float xv;
        if (IN_IS_WS) xv = ((const float*)in)[(size_t)row * 64 + lane];
        else          xv = loadF(in, (size_t)row * 64 + lane, isF32);
        if (RELU) xv = fmaxf(xv, 0.0f);
        float acc = 0.0f;
#pragma unroll
        for (int k = 0; k < 64; ++k) {
            float xk = __shfl(xv, k, 64);
            acc = fmaf(xk, Wl[k * 64 + lane], acc);
        }
        out[(size_t)row * 64 + lane] = acc;
    }
}

// ---------------- accumulator init: agg = h * dinv^2 + b ----------------
__global__ void selfinit_kernel(const float* __restrict__ h, const float* __restrict__ dinv,
                                const void* __restrict__ b, float* __restrict__ agg, int total,
                                const int* __restrict__ flags) {
    int idx = blockIdx.x * blockDim.x + threadIdx.x;
    if (idx < total) {
        int i = idx >> 6, j = idx & 63;
        float d = dinv[i];
        agg[idx] = fmaf(h[idx], d * d, loadF(b, j, flags[1]));
    }
}

// ---------------- edge scatter: agg[dst] += h[src] * dinv[src]*dinv[dst] ----------------
__global__ void scatter_kernel(const void* __restrict__ edge, long long dstOff,
                               const float* __restrict__ dinv, const float* __restrict__ h,
                               float* __restrict__ agg, int E, int edgesPerWave,
                               const int* __restrict__ flags) {
    const int is64 = flags[0];
    const int lane = threadIdx.x & 63;
    const int wave = (blockIdx.x * blockDim.x + threadIdx.x) >> 6;
    int e0 = wave * edgesPerWave;
    int e1 = min(e0 + edgesPerWave, E);
    for (int e = e0; e < e1; ++e) {
        int s = getIdx(edge, e, is64);
        int d = getIdx(edge, dstOff + e, is64);
        float c = dinv[s] * dinv[d];
        float v = h[(size_t)s * 64 + lane] * c;
        atomicAdd(&agg[(size_t)d * 64 + lane], v);
    }
}

// ---------------- heads ----------------
// mode 0: yi -> out[0:N], fprob -> out[N:2N], treat_prob -> out[3N:4N]
// mode 1: fprob_f -> out[2N:3N]
__global__ void final_kernel(const float* __restrict__ xZ2,
                             const void* __restrict__ Wy, const void* __restrict__ by,
                             const void* __restrict__ Wp, const void* __restrict__ bp,
                             const void* __restrict__ Wb, const void* __restrict__ bb,
                             void* __restrict__ out, int N, int mode,
                             const int* __restrict__ flags) {
    const int isF32 = flags[1];
    const int lane = threadIdx.x & 63;
    const int wpb  = blockDim.x >> 6;
    int i = blockIdx.x * wpb + (threadIdx.x >> 6);
    if (i >= N) return;
    float x = xZ2[(size_t)i * 64 + lane];
    if (mode == 0) {
        float ry = x * loadF(Wy, lane, isF32);
        float rp = x * loadF(Wp, lane, isF32);
        float rb = x * loadF(Wb, lane, isF32);
#pragma unroll
        for (int off = 32; off > 0; off >>= 1) {
            ry += __shfl_xor(ry, off, 64);
            rp += __shfl_xor(rp, off, 64);
            rb += __shfl_xor(rb, off, 64);
        }
        if (lane == 0) {
            storeF(out, (size_t)i,         fmaxf(ry + loadF(by, 0, isF32), 0.0f), isF32);
            storeF(out, (size_t)N + i,     fmaxf(rp + loadF(bp, 0, isF32), 0.0f), isF32);
            storeF(out, (size_t)3 * N + i, fmaxf(rb + loadF(bb, 0, isF32), 0.0f), isF32);
        }
    } else {
        float rp = x * loadF(Wp, lane, isF32);
#pragma unroll
        for (int off = 32; off > 0; off >>= 1) rp += __shfl_xor(rp, off, 64);
        if (lane == 0)
            storeF(out, (size_t)2 * N + i, fmaxf(rp + loadF(bp, 0, isF32), 0.0f), isF32);
    }
}

extern "C" void kernel_launch(void* const* d_in, const int* in_sizes, int n_in,
                              void* d_out, int out_size, void* d_ws, size_t ws_size,
                              hipStream_t stream) {
    const void* x   = d_in[0];
    const void* ei  = d_in[1];
    const void* fx  = d_in[2];
    const void* fei = d_in[3];
    const void* W1  = d_in[4];
    const void* b1  = d_in[5];
    const void* W2  = d_in[6];
    const void* b2  = d_in[7];
    const void* Wy  = d_in[8];
    const void* by  = d_in[9];
    const void* Wp  = d_in[10];
    const void* bp  = d_in[11];
    const void* Wb  = d_in[12];
    const void* bb  = d_in[13];

    const int N = in_sizes[0] / 64;
    const int E = in_sizes[1] / 2;

    // ws layout: flags[16] (int) | deg[N] (int) | dinv[N] (f32) | bufA[N*64] | bufB[N*64]
    int*   flags = (int*)d_ws;
    int*   deg   = flags + 16;
    float* dinv  = (float*)(deg + N);
    float* bufA  = dinv + N;
    float* bufB  = bufA + (size_t)N * 64;

    const int THREADS = 256;
    const int totalWaves   = 32768;
    const int edgesPerWave = (E + totalWaves - 1) / totalWaves;

    detect_kernel<<<1, 64, 0, stream>>>(ei, x, flags);

    for (int g = 0; g < 2; ++g) {
        const void* xg   = g ? fx : x;
        const void* edge = g ? fei : ei;
        const long long dstOff = E;   // dst row follows src row (element offset)

        hipMemsetAsync(deg, 0, (size_t)N * sizeof(int), stream);
        degree_kernel<<<(E + THREADS - 1) / THREADS, THREADS, 0, stream>>>(edge, dstOff, E, deg, flags);
        dinv_kernel<<<(N + THREADS - 1) / THREADS, THREADS, 0, stream>>>(deg, dinv, N);

        // layer 1
        gemm64_kernel<false, false><<<2048, THREADS, 0, stream>>>(xg, W1, bufA, N, flags);
        selfinit_kernel<<<(N * 64 + THREADS - 1) / THREADS, THREADS, 0, stream>>>(bufA, dinv, b1, bufB, N * 64, flags);
        scatter_kernel<<<totalWaves / 4, THREADS, 0, stream>>>(edge, dstOff, dinv, bufA, bufB, E, edgesPerWave, flags);

        // layer 2 (relu fused into GEMM load)
        gemm64_kernel<true, true><<<2048, THREADS, 0, stream>>>(bufB, W2, bufA, N, flags);
        selfinit_kernel<<<(N * 64 + THREADS - 1) / THREADS, THREADS, 0, stream>>>(bufA, dinv, b2, bufB, N * 64, flags);
        scatter_kernel<<<totalWaves / 4, THREADS, 0, stream>>>(edge, dstOff, dinv, bufA, bufB, E, edgesPerWave, flags);

        // heads
        final_kernel<<<(N + 3) / 4, THREADS, 0, stream>>>(bufB, Wy, by, Wp, bp, Wb, bb, d_out, N, g, flags);
    }
}

// Round 4
// 1277.792 us; speedup vs baseline: 1.5521x; 1.5521x over previous
//
#include <hip/hip_runtime.h>
#include <hip/hip_bf16.h>

typedef __hip_bfloat16 bf16;

__device__ __forceinline__ float b2f(bf16 v) { return __bfloat162float(v); }

// flags[0] = 1 if edge_index is int64, 0 if int32
// flags[1] = 1 if float tensors (and output) are fp32, 0 if bf16
__global__ void detect_kernel(const void* __restrict__ edge, const void* __restrict__ x,
                              int* __restrict__ flags) {
    if (blockIdx.x != 0 || threadIdx.x != 0) return;
    const int* e32 = (const int*)edge;
    int allzero = 1;
    for (int k = 1; k < 1024; k += 2)       if (e32[k] != 0) { allzero = 0; break; }
    if (allzero)
        for (int k = 1000001; k < 1002048; k += 2) if (e32[k] != 0) { allzero = 0; break; }
    flags[0] = allzero;
    const unsigned short* u = (const unsigned short*)x;
    int insane = 0;
    for (int k = 0; k < 512; k += 2) {
        int ex = (u[k] >> 7) & 0xFF;
        if (ex != 0 && (ex < 90 || ex > 160)) insane++;
    }
    flags[1] = (insane > 64) ? 1 : 0;
}

__device__ __forceinline__ int getIdx(const void* p, long long i, int is64) {
    return is64 ? (int)(((const long long*)p)[i]) : ((const int*)p)[i];
}
__device__ __forceinline__ float loadF(const void* p, size_t i, int isF32) {
    return isF32 ? ((const float*)p)[i] : b2f(((const bf16*)p)[i]);
}
__device__ __forceinline__ void storeF(void* p, size_t i, float v, int isF32) {
    if (isF32) ((float*)p)[i] = v;
    else       ((bf16*)p)[i]  = __float2bfloat16(v);
}

// ---------------- degree histogram (raw in-degree, no self-loop) ----------------
__global__ void degree_kernel(const void* __restrict__ edge, long long dstOff, int E,
                              int* __restrict__ deg, const int* __restrict__ flags) {
    int e = blockIdx.x * blockDim.x + threadIdx.x;
    if (e < E) atomicAdd(&deg[getIdx(edge, dstOff + e, flags[0])], 1);
}

__global__ void dinv_kernel(const int* __restrict__ deg, float* __restrict__ dinv, int N) {
    int i = blockIdx.x * blockDim.x + threadIdx.x;
    if (i < N) dinv[i] = rsqrtf((float)deg[i] + 1.0f);   // +1 self-loop
}

// ---------------- exclusive scan of deg -> rowptr (3 kernels) ----------------
__global__ void scan1_kernel(const int* __restrict__ deg, int* __restrict__ rowptr,
                             int* __restrict__ blockSums, int N) {
    __shared__ int tmp[256];
    int gid = blockIdx.x * 256 + threadIdx.x;
    int v = (gid < N) ? deg[gid] : 0;
    tmp[threadIdx.x] = v;
    __syncthreads();
#pragma unroll
    for (int off = 1; off < 256; off <<= 1) {
        int t = (threadIdx.x >= off) ? tmp[threadIdx.x - off] : 0;
        __syncthreads();
        tmp[threadIdx.x] += t;
        __syncthreads();
    }
    if (gid < N) rowptr[gid] = tmp[threadIdx.x] - v;          // exclusive (block-local)
    if (threadIdx.x == 255) blockSums[blockIdx.x] = tmp[255]; // block total
}

__global__ void scan2_kernel(int* __restrict__ blockSums, int nb) {
    __shared__ int tmp[512];
    int v = (threadIdx.x < nb) ? blockSums[threadIdx.x] : 0;
    tmp[threadIdx.x] = v;
    __syncthreads();
#pragma unroll
    for (int off = 1; off < 512; off <<= 1) {
        int t = (threadIdx.x >= off) ? tmp[threadIdx.x - off] : 0;
        __syncthreads();
        tmp[threadIdx.x] += t;
        __syncthreads();
    }
    if (threadIdx.x < nb) blockSums[threadIdx.x] = tmp[threadIdx.x] - v;  // exclusive
}

__global__ void scan3_kernel(int* __restrict__ rowptr, const int* __restrict__ blockSums,
                             int* __restrict__ cursor, int N, int E) {
    int gid = blockIdx.x * 256 + threadIdx.x;
    if (gid < N) {
        int v = rowptr[gid] + blockSums[blockIdx.x];
        rowptr[gid] = v;
        cursor[gid] = v;
    }
    if (gid == 0) rowptr[N] = E;
}

// ---------------- CSR placement: csr_src[pos] = src, grouped by dst ----------------
__global__ void place_kernel(const void* __restrict__ edge, long long dstOff, int E,
                             int* __restrict__ cursor, int* __restrict__ csr_src,
                             const int* __restrict__ flags) {
    int e = blockIdx.x * blockDim.x + threadIdx.x;
    if (e < E) {
        int is64 = flags[0];
        int s = getIdx(edge, e, is64);
        int d = getIdx(edge, dstOff + e, is64);
        int pos = atomicAdd(&cursor[d], 1);
        csr_src[pos] = s;
    }
}

// ---------------- GEMM: out[N,64] = (relu?)in[N,64] @ W[64,64] ----------------
template <bool RELU, bool IN_IS_WS>
__global__ void gemm64_kernel(const void* __restrict__ in, const void* __restrict__ W,
                              float* __restrict__ out, int N, const int* __restrict__ flags) {
    __shared__ float Wl[64 * 64];
    const int isF32 = flags[1];
    for (int t = threadIdx.x; t < 64 * 64; t += blockDim.x) Wl[t] = loadF(W, t, isF32);
    __syncthreads();
    const int lane = threadIdx.x & 63;
    const int wpb  = blockDim.x >> 6;
    int row = blockIdx.x * wpb + (threadIdx.x >> 6);
    const int stride = gridDim.x * wpb;
    for (; row < N; row += stride) {
        float xv;
        if (IN_IS_WS) xv = ((const float*)in)[(size_t)row * 64 + lane];
        else          xv = loadF(in, (size_t)row * 64 + lane, isF32);
        if (RELU) xv = fmaxf(xv, 0.0f);
        float acc = 0.0f;
#pragma unroll
        for (int k = 0; k < 64; ++k) {
            float xk = __shfl(xv, k, 64);
            acc = fmaf(xk, Wl[k * 64 + lane], acc);
        }
        out[(size_t)row * 64 + lane] = acc;
    }
}

// ---------------- gather: out[i] = (sum_s h[s]*dinv[s] + h[i]*dinv[i])*dinv[i] + b ----------------
// One wave per destination node; lane = feature. No atomics.
__global__ void gather_kernel(const int* __restrict__ csr_src, const int* __restrict__ rowptr,
                              const float* __restrict__ dinv, const float* __restrict__ h,
                              const void* __restrict__ bias, float* __restrict__ out,
                              int N, const int* __restrict__ flags) {
    const int isF32 = flags[1];
    const int lane = threadIdx.x & 63;
    int i = blockIdx.x * (blockDim.x >> 6) + (threadIdx.x >> 6);
    if (i >= N) return;
    const int beg = rowptr[i];
    const int end = rowptr[i + 1];
    const float di = dinv[i];
    float acc0 = 0.0f, acc1 = 0.0f;
    int e = beg;
    for (; e + 1 < end; e += 2) {
        int s0 = csr_src[e];
        int s1 = csr_src[e + 1];
        float c0 = dinv[s0];
        float c1 = dinv[s1];
        acc0 = fmaf(h[(size_t)s0 * 64 + lane], c0, acc0);
        acc1 = fmaf(h[(size_t)s1 * 64 + lane], c1, acc1);
    }
    if (e < end) {
        int s = csr_src[e];
        acc0 = fmaf(h[(size_t)s * 64 + lane], dinv[s], acc0);
    }
    float hs  = h[(size_t)i * 64 + lane];
    float tot = fmaf(hs, di, acc0 + acc1);
    out[(size_t)i * 64 + lane] = fmaf(tot, di, loadF(bias, lane, isF32));
}

// ---------------- heads ----------------
__global__ void final_kernel(const float* __restrict__ xZ2,
                             const void* __restrict__ Wy, const void* __restrict__ by,
                             const void* __restrict__ Wp, const void* __restrict__ bp,
                             const void* __restrict__ Wb, const void* __restrict__ bb,
                             void* __restrict__ out, int N, int mode,
                             const int* __restrict__ flags) {
    const int isF32 = flags[1];
    const int lane = threadIdx.x & 63;
    const int wpb  = blockDim.x >> 6;
    int i = blockIdx.x * wpb + (threadIdx.x >> 6);
    if (i >= N) return;
    float x = xZ2[(size_t)i * 64 + lane];
    if (mode == 0) {
        float ry = x * loadF(Wy, lane, isF32);
        float rp = x * loadF(Wp, lane, isF32);
        float rb = x * loadF(Wb, lane, isF32);
#pragma unroll
        for (int off = 32; off > 0; off >>= 1) {
            ry += __shfl_xor(ry, off, 64);
            rp += __shfl_xor(rp, off, 64);
            rb += __shfl_xor(rb, off, 64);
        }
        if (lane == 0) {
            storeF(out, (size_t)i,         fmaxf(ry + loadF(by, 0, isF32), 0.0f), isF32);
            storeF(out, (size_t)N + i,     fmaxf(rp + loadF(bp, 0, isF32), 0.0f), isF32);
            storeF(out, (size_t)3 * N + i, fmaxf(rb + loadF(bb, 0, isF32), 0.0f), isF32);
        }
    } else {
        float rp = x * loadF(Wp, lane, isF32);
#pragma unroll
        for (int off = 32; off > 0; off >>= 1) rp += __shfl_xor(rp, off, 64);
        if (lane == 0)
            storeF(out, (size_t)2 * N + i, fmaxf(rp + loadF(bp, 0, isF32), 0.0f), isF32);
    }
}

extern "C" void kernel_launch(void* const* d_in, const int* in_sizes, int n_in,
                              void* d_out, int out_size, void* d_ws, size_t ws_size,
                              hipStream_t stream) {
    const void* x   = d_in[0];
    const void* ei  = d_in[1];
    const void* fx  = d_in[2];
    const void* fei = d_in[3];
    const void* W1  = d_in[4];
    const void* b1  = d_in[5];
    const void* W2  = d_in[6];
    const void* b2  = d_in[7];
    const void* Wy  = d_in[8];
    const void* by  = d_in[9];
    const void* Wp  = d_in[10];
    const void* bp  = d_in[11];
    const void* Wb  = d_in[12];
    const void* bb  = d_in[13];

    const int N = in_sizes[0] / 64;
    const int E = in_sizes[1] / 2;

    // ws layout (ints first, then floats):
    // flags[16] | deg[N] | rowptr[N+1] | cursor[N] | blockSums[1024] | csr_src[E]
    // | dinv[N] f32 | bufA[N*64] f32 | bufB[N*64] f32
    int*   flags     = (int*)d_ws;
    int*   deg       = flags + 16;
    int*   rowptr    = deg + N;
    int*   cursor    = rowptr + (N + 1);
    int*   blockSums = cursor + N;
    int*   csr_src   = blockSums + 1024;
    float* dinv      = (float*)(csr_src + E);
    float* bufA      = dinv + N;
    float* bufB      = bufA + (size_t)N * 64;

    const int THREADS = 256;
    const int nbN = (N + 255) / 256;       // scan blocking (391 for N=100000, fits 512)
    const int nbE = (E + THREADS - 1) / THREADS;

    detect_kernel<<<1, 64, 0, stream>>>(ei, x, flags);

    for (int g = 0; g < 2; ++g) {
        const void* xg   = g ? fx : x;
        const void* edge = g ? fei : ei;
        const long long dstOff = E;

        // ---- CSR build (shared by both layers) ----
        hipMemsetAsync(deg, 0, (size_t)N * sizeof(int), stream);
        degree_kernel<<<nbE, THREADS, 0, stream>>>(edge, dstOff, E, deg, flags);
        dinv_kernel<<<nbN, 256, 0, stream>>>(deg, dinv, N);
        scan1_kernel<<<nbN, 256, 0, stream>>>(deg, rowptr, blockSums, N);
        scan2_kernel<<<1, 512, 0, stream>>>(blockSums, nbN);
        scan3_kernel<<<nbN, 256, 0, stream>>>(rowptr, blockSums, cursor, N, E);
        place_kernel<<<nbE, THREADS, 0, stream>>>(edge, dstOff, E, cursor, csr_src, flags);

        // ---- layer 1 ----
        gemm64_kernel<false, false><<<2048, THREADS, 0, stream>>>(xg, W1, bufA, N, flags);
        gather_kernel<<<(N + 3) / 4, THREADS, 0, stream>>>(csr_src, rowptr, dinv, bufA, b1, bufB, N, flags);

        // ---- layer 2 (relu fused into GEMM load) ----
        gemm64_kernel<true, true><<<2048, THREADS, 0, stream>>>(bufB, W2, bufA, N, flags);
        gather_kernel<<<(N + 3) / 4, THREADS, 0, stream>>>(csr_src, rowptr, dinv, bufA, b2, bufB, N, flags);

        // ---- heads ----
        final_kernel<<<(N + 3) / 4, THREADS, 0, stream>>>(bufB, Wy, by, Wp, bp, Wb, bb, d_out, N, g, flags);
    }
}

// Round 5
// 1177.636 us; speedup vs baseline: 1.6841x; 1.0850x over previous
//
#include <hip/hip_runtime.h>
#include <hip/hip_bf16.h>

typedef __hip_bfloat16 bf16;

__device__ __forceinline__ float b2f(bf16 v) { return __bfloat162float(v); }

// flags[0] = 1 if edge_index is int64, 0 if int32
// flags[1] = 1 if float tensors (and output) are fp32, 0 if bf16
__global__ void detect_kernel(const void* __restrict__ edge, const void* __restrict__ x,
                              int* __restrict__ flags) {
    if (blockIdx.x != 0 || threadIdx.x != 0) return;
    const int* e32 = (const int*)edge;
    int allzero = 1;
    for (int k = 1; k < 1024; k += 2)       if (e32[k] != 0) { allzero = 0; break; }
    if (allzero)
        for (int k = 1000001; k < 1002048; k += 2) if (e32[k] != 0) { allzero = 0; break; }
    flags[0] = allzero;
    const unsigned short* u = (const unsigned short*)x;
    int insane = 0;
    for (int k = 0; k < 512; k += 2) {
        int ex = (u[k] >> 7) & 0xFF;
        if (ex != 0 && (ex < 90 || ex > 160)) insane++;
    }
    flags[1] = (insane > 64) ? 1 : 0;
}

__device__ __forceinline__ int getIdx(const void* p, long long i, int is64) {
    return is64 ? (int)(((const long long*)p)[i]) : ((const int*)p)[i];
}
__device__ __forceinline__ float loadF(const void* p, size_t i, int isF32) {
    return isF32 ? ((const float*)p)[i] : b2f(((const bf16*)p)[i]);
}
__device__ __forceinline__ void storeF(void* p, size_t i, float v, int isF32) {
    if (isF32) ((float*)p)[i] = v;
    else       ((bf16*)p)[i]  = __float2bfloat16(v);
}

// ---------------- degree histogram (raw in-degree, no self-loop) ----------------
__global__ void degree_kernel(const void* __restrict__ edge, long long dstOff, int E,
                              int* __restrict__ deg, const int* __restrict__ flags) {
    int e = blockIdx.x * blockDim.x + threadIdx.x;
    if (e < E) atomicAdd(&deg[getIdx(edge, dstOff + e, flags[0])], 1);
}

__global__ void dinv_kernel(const int* __restrict__ deg, float* __restrict__ dinv, int N) {
    int i = blockIdx.x * blockDim.x + threadIdx.x;
    if (i < N) dinv[i] = rsqrtf((float)deg[i] + 1.0f);   // +1 self-loop
}

// ---------------- exclusive scan of deg -> rowptr (3 kernels) ----------------
__global__ void scan1_kernel(const int* __restrict__ deg, int* __restrict__ rowptr,
                             int* __restrict__ blockSums, int N) {
    __shared__ int tmp[256];
    int gid = blockIdx.x * 256 + threadIdx.x;
    int v = (gid < N) ? deg[gid] : 0;
    tmp[threadIdx.x] = v;
    __syncthreads();
#pragma unroll
    for (int off = 1; off < 256; off <<= 1) {
        int t = (threadIdx.x >= off) ? tmp[threadIdx.x - off] : 0;
        __syncthreads();
        tmp[threadIdx.x] += t;
        __syncthreads();
    }
    if (gid < N) rowptr[gid] = tmp[threadIdx.x] - v;
    if (threadIdx.x == 255) blockSums[blockIdx.x] = tmp[255];
}

__global__ void scan2_kernel(int* __restrict__ blockSums, int nb) {
    __shared__ int tmp[512];
    int v = (threadIdx.x < nb) ? blockSums[threadIdx.x] : 0;
    tmp[threadIdx.x] = v;
    __syncthreads();
#pragma unroll
    for (int off = 1; off < 512; off <<= 1) {
        int t = (threadIdx.x >= off) ? tmp[threadIdx.x - off] : 0;
        __syncthreads();
        tmp[threadIdx.x] += t;
        __syncthreads();
    }
    if (threadIdx.x < nb) blockSums[threadIdx.x] = tmp[threadIdx.x] - v;
}

__global__ void scan3_kernel(int* __restrict__ rowptr, const int* __restrict__ blockSums,
                             int* __restrict__ cursor, int N, int E) {
    int gid = blockIdx.x * 256 + threadIdx.x;
    if (gid < N) {
        int v = rowptr[gid] + blockSums[blockIdx.x];
        rowptr[gid] = v;
        cursor[gid] = v;
    }
    if (gid == 0) rowptr[N] = E;
}

// ---------------- CSR placement ----------------
__global__ void place_kernel(const void* __restrict__ edge, long long dstOff, int E,
                             int* __restrict__ cursor, int* __restrict__ csr_src,
                             const int* __restrict__ flags) {
    int e = blockIdx.x * blockDim.x + threadIdx.x;
    if (e < E) {
        int is64 = flags[0];
        int s = getIdx(edge, e, is64);
        int d = getIdx(edge, dstOff + e, is64);
        int pos = atomicAdd(&cursor[d], 1);
        csr_src[pos] = s;
    }
}

// ---------------- GEMM + dinv premultiply: out[r] = ((relu?)in[r] @ W) * dinv[r] ----------------
// One wave per row; lane's W column held in 64 VGPRs; xk broadcast via shfl.
template <bool RELU, bool IN_IS_WS>
__global__ void gemm64_kernel(const void* __restrict__ in, const void* __restrict__ W,
                              const float* __restrict__ dinv, float* __restrict__ out,
                              int N, const int* __restrict__ flags) {
    const int isF32 = flags[1];
    const int lane = threadIdx.x & 63;
    float w[64];
#pragma unroll
    for (int k = 0; k < 64; ++k) w[k] = loadF(W, (size_t)k * 64 + lane, isF32);  // W[k][lane]
    const int wpb  = blockDim.x >> 6;
    int row = blockIdx.x * wpb + (threadIdx.x >> 6);
    const int stride = gridDim.x * wpb;
    for (; row < N; row += stride) {
        float xv;
        if (IN_IS_WS) xv = ((const float*)in)[(size_t)row * 64 + lane];
        else          xv = loadF(in, (size_t)row * 64 + lane, isF32);
        if (RELU) xv = fmaxf(xv, 0.0f);
        float acc = 0.0f;
#pragma unroll
        for (int k = 0; k < 64; ++k) {
            acc = fmaf(__shfl(xv, k, 64), w[k], acc);
        }
        out[(size_t)row * 64 + lane] = acc * dinv[row];
    }
}

// ---------------- gather: out[i] = dinv[i]*(sum_s h'[s] + h'[i]) + b,  h' = h*dinv ----------------
// One wave per dst node: 16 lanes x float4 per row, 4 edge slots, unroll x2.
__global__ void gather_kernel(const int* __restrict__ csr_src, const int* __restrict__ rowptr,
                              const float* __restrict__ dinv, const float* __restrict__ hp,
                              const void* __restrict__ bias, float* __restrict__ out,
                              int N, const int* __restrict__ flags) {
    const int isF32 = flags[1];
    const int lane = threadIdx.x & 63;
    const int slot = lane >> 4;          // 0..3  edge slot
    const int fi   = lane & 15;          // feature quarter (4 floats)
    int i = blockIdx.x * (blockDim.x >> 6) + (threadIdx.x >> 6);
    if (i >= N) return;
    const int beg = rowptr[i];
    const int end = rowptr[i + 1];
    const float4* __restrict__ h4 = (const float4*)hp;

    float4 a0 = make_float4(0.f, 0.f, 0.f, 0.f);
    float4 a1 = make_float4(0.f, 0.f, 0.f, 0.f);
    int e = beg + slot;
    for (; e + 4 < end; e += 8) {
        int s0 = csr_src[e];
        int s1 = csr_src[e + 4];
        float4 v0 = h4[(size_t)s0 * 16 + fi];
        float4 v1 = h4[(size_t)s1 * 16 + fi];
        a0.x += v0.x; a0.y += v0.y; a0.z += v0.z; a0.w += v0.w;
        a1.x += v1.x; a1.y += v1.y; a1.z += v1.z; a1.w += v1.w;
    }
    if (e < end) {
        int s = csr_src[e];
        float4 v = h4[(size_t)s * 16 + fi];
        a0.x += v.x; a0.y += v.y; a0.z += v.z; a0.w += v.w;
    }
    a0.x += a1.x; a0.y += a1.y; a0.z += a1.z; a0.w += a1.w;
    // reduce across the 4 edge slots (xor 16, 32)
    a0.x += __shfl_xor(a0.x, 16, 64); a0.y += __shfl_xor(a0.y, 16, 64);
    a0.z += __shfl_xor(a0.z, 16, 64); a0.w += __shfl_xor(a0.w, 16, 64);
    a0.x += __shfl_xor(a0.x, 32, 64); a0.y += __shfl_xor(a0.y, 32, 64);
    a0.z += __shfl_xor(a0.z, 32, 64); a0.w += __shfl_xor(a0.w, 32, 64);

    if (slot == 0) {
        const float di = dinv[i];
        float4 hi = h4[(size_t)i * 16 + fi];
        float4 r;
        r.x = fmaf(a0.x + hi.x, di, loadF(bias, fi * 4 + 0, isF32));
        r.y = fmaf(a0.y + hi.y, di, loadF(bias, fi * 4 + 1, isF32));
        r.z = fmaf(a0.z + hi.z, di, loadF(bias, fi * 4 + 2, isF32));
        r.w = fmaf(a0.w + hi.w, di, loadF(bias, fi * 4 + 3, isF32));
        ((float4*)out)[(size_t)i * 16 + fi] = r;
    }
}

// ---------------- heads ----------------
__global__ void final_kernel(const float* __restrict__ xZ2,
                             const void* __restrict__ Wy, const void* __restrict__ by,
                             const void* __restrict__ Wp, const void* __restrict__ bp,
                             const void* __restrict__ Wb, const void* __restrict__ bb,
                             void* __restrict__ out, int N, int mode,
                             const int* __restrict__ flags) {
    const int isF32 = flags[1];
    const int lane = threadIdx.x & 63;
    const int wpb  = blockDim.x >> 6;
    int i = blockIdx.x * wpb + (threadIdx.x >> 6);
    if (i >= N) return;
    float x = xZ2[(size_t)i * 64 + lane];
    if (mode == 0) {
        float ry = x * loadF(Wy, lane, isF32);
        float rp = x * loadF(Wp, lane, isF32);
        float rb = x * loadF(Wb, lane, isF32);
#pragma unroll
        for (int off = 32; off > 0; off >>= 1) {
            ry += __shfl_xor(ry, off, 64);
            rp += __shfl_xor(rp, off, 64);
            rb += __shfl_xor(rb, off, 64);
        }
        if (lane == 0) {
            storeF(out, (size_t)i,         fmaxf(ry + loadF(by, 0, isF32), 0.0f), isF32);
            storeF(out, (size_t)N + i,     fmaxf(rp + loadF(bp, 0, isF32), 0.0f), isF32);
            storeF(out, (size_t)3 * N + i, fmaxf(rb + loadF(bb, 0, isF32), 0.0f), isF32);
        }
    } else {
        float rp = x * loadF(Wp, lane, isF32);
#pragma unroll
        for (int off = 32; off > 0; off >>= 1) rp += __shfl_xor(rp, off, 64);
        if (lane == 0)
            storeF(out, (size_t)2 * N + i, fmaxf(rp + loadF(bp, 0, isF32), 0.0f), isF32);
    }
}

extern "C" void kernel_launch(void* const* d_in, const int* in_sizes, int n_in,
                              void* d_out, int out_size, void* d_ws, size_t ws_size,
                              hipStream_t stream) {
    const void* x   = d_in[0];
    const void* ei  = d_in[1];
    const void* fx  = d_in[2];
    const void* fei = d_in[3];
    const void* W1  = d_in[4];
    const void* b1  = d_in[5];
    const void* W2  = d_in[6];
    const void* b2  = d_in[7];
    const void* Wy  = d_in[8];
    const void* by  = d_in[9];
    const void* Wp  = d_in[10];
    const void* bp  = d_in[11];
    const void* Wb  = d_in[12];
    const void* bb  = d_in[13];

    const int N = in_sizes[0] / 64;
    const int E = in_sizes[1] / 2;

    // ws layout (ints first, then floats):
    // flags[16] | deg[N] | rowptr[N+1] | cursor[N] | blockSums[1024] | csr_src[E]
    // | dinv[N] f32 | bufA[N*64] f32 (h', 16B aligned) | bufB[N*64] f32
    int*   flags     = (int*)d_ws;
    int*   deg       = flags + 16;
    int*   rowptr    = deg + N;
    int*   cursor    = rowptr + (N + 1);
    int*   blockSums = cursor + N;
    int*   csr_src   = blockSums + 1024;
    float* dinv      = (float*)(csr_src + E);
    // align bufA to 16 B for float4 access
    size_t off = ((size_t)(dinv + N) + 15) & ~(size_t)15;
    float* bufA      = (float*)off;
    float* bufB      = bufA + (size_t)N * 64;

    const int THREADS = 256;
    const int nbN = (N + 255) / 256;
    const int nbE = (E + THREADS - 1) / THREADS;

    detect_kernel<<<1, 64, 0, stream>>>(ei, x, flags);

    for (int g = 0; g < 2; ++g) {
        const void* xg   = g ? fx : x;
        const void* edge = g ? fei : ei;
        const long long dstOff = E;

        // ---- CSR build (shared by both layers) ----
        hipMemsetAsync(deg, 0, (size_t)N * sizeof(int), stream);
        degree_kernel<<<nbE, THREADS, 0, stream>>>(edge, dstOff, E, deg, flags);
        dinv_kernel<<<nbN, 256, 0, stream>>>(deg, dinv, N);
        scan1_kernel<<<nbN, 256, 0, stream>>>(deg, rowptr, blockSums, N);
        scan2_kernel<<<1, 512, 0, stream>>>(blockSums, nbN);
        scan3_kernel<<<nbN, 256, 0, stream>>>(rowptr, blockSums, cursor, N, E);
        place_kernel<<<nbE, THREADS, 0, stream>>>(edge, dstOff, E, cursor, csr_src, flags);

        // ---- layer 1 ----
        gemm64_kernel<false, false><<<2048, THREADS, 0, stream>>>(xg, W1, dinv, bufA, N, flags);
        gather_kernel<<<(N + 3) / 4, THREADS, 0, stream>>>(csr_src, rowptr, dinv, bufA, b1, bufB, N, flags);

        // ---- layer 2 (relu fused into GEMM load) ----
        gemm64_kernel<true, true><<<2048, THREADS, 0, stream>>>(bufB, W2, dinv, bufA, N, flags);
        gather_kernel<<<(N + 3) / 4, THREADS, 0, stream>>>(csr_src, rowptr, dinv, bufA, b2, bufB, N, flags);

        // ---- heads ----
        final_kernel<<<(N + 3) / 4, THREADS, 0, stream>>>(bufB, Wy, by, Wp, bp, Wb, bb, d_out, N, g, flags);
    }
}

// Round 6
// 1111.780 us; speedup vs baseline: 1.7839x; 1.0592x over previous
//
#include <hip/hip_runtime.h>
#include <hip/hip_bf16.h>

typedef __hip_bfloat16 bf16;

__device__ __forceinline__ float b2f(bf16 v) { return __bfloat162float(v); }

// flags[0] = 1 if edge_index is int64, 0 if int32
// flags[1] = 1 if float tensors (and output) are fp32, 0 if bf16
__global__ void detect_kernel(const void* __restrict__ edge, const void* __restrict__ x,
                              int* __restrict__ flags) {
    if (blockIdx.x != 0 || threadIdx.x != 0) return;
    const int* e32 = (const int*)edge;
    int allzero = 1;
    for (int k = 1; k < 1024; k += 2)       if (e32[k] != 0) { allzero = 0; break; }
    if (allzero)
        for (int k = 1000001; k < 1002048; k += 2) if (e32[k] != 0) { allzero = 0; break; }
    flags[0] = allzero;
    const unsigned short* u = (const unsigned short*)x;
    int insane = 0;
    for (int k = 0; k < 512; k += 2) {
        int ex = (u[k] >> 7) & 0xFF;
        if (ex != 0 && (ex < 90 || ex > 160)) insane++;
    }
    flags[1] = (insane > 64) ? 1 : 0;
}

__device__ __forceinline__ int getIdx(const void* p, long long i, int is64) {
    return is64 ? (int)(((const long long*)p)[i]) : ((const int*)p)[i];
}
__device__ __forceinline__ float loadF(const void* p, size_t i, int isF32) {
    return isF32 ? ((const float*)p)[i] : b2f(((const bf16*)p)[i]);
}
__device__ __forceinline__ void storeF(void* p, size_t i, float v, int isF32) {
    if (isF32) ((float*)p)[i] = v;
    else       ((bf16*)p)[i]  = __float2bfloat16(v);
}

// ---------------- degree histogram (raw in-degree, no self-loop) ----------------
__global__ void degree_kernel(const void* __restrict__ edge, long long dstOff, int E,
                              int* __restrict__ deg, const int* __restrict__ flags) {
    int e = blockIdx.x * blockDim.x + threadIdx.x;
    if (e < E) atomicAdd(&deg[getIdx(edge, dstOff + e, flags[0])], 1);
}

__global__ void dinv_kernel(const int* __restrict__ deg, float* __restrict__ dinv, int N) {
    int i = blockIdx.x * blockDim.x + threadIdx.x;
    if (i < N) dinv[i] = rsqrtf((float)deg[i] + 1.0f);   // +1 self-loop
}

// ---------------- exclusive scan of deg -> rowptr (3 kernels) ----------------
__global__ void scan1_kernel(const int* __restrict__ deg, int* __restrict__ rowptr,
                             int* __restrict__ blockSums, int N) {
    __shared__ int tmp[256];
    int gid = blockIdx.x * 256 + threadIdx.x;
    int v = (gid < N) ? deg[gid] : 0;
    tmp[threadIdx.x] = v;
    __syncthreads();
#pragma unroll
    for (int off = 1; off < 256; off <<= 1) {
        int t = (threadIdx.x >= off) ? tmp[threadIdx.x - off] : 0;
        __syncthreads();
        tmp[threadIdx.x] += t;
        __syncthreads();
    }
    if (gid < N) rowptr[gid] = tmp[threadIdx.x] - v;
    if (threadIdx.x == 255) blockSums[blockIdx.x] = tmp[255];
}

__global__ void scan2_kernel(int* __restrict__ blockSums, int nb) {
    __shared__ int tmp[512];
    int v = (threadIdx.x < nb) ? blockSums[threadIdx.x] : 0;
    tmp[threadIdx.x] = v;
    __syncthreads();
#pragma unroll
    for (int off = 1; off < 512; off <<= 1) {
        int t = (threadIdx.x >= off) ? tmp[threadIdx.x - off] : 0;
        __syncthreads();
        tmp[threadIdx.x] += t;
        __syncthreads();
    }
    if (threadIdx.x < nb) blockSums[threadIdx.x] = tmp[threadIdx.x] - v;
}

__global__ void scan3_kernel(int* __restrict__ rowptr, const int* __restrict__ blockSums,
                             int* __restrict__ cursor, int N, int E) {
    int gid = blockIdx.x * 256 + threadIdx.x;
    if (gid < N) {
        int v = rowptr[gid] + blockSums[blockIdx.x];
        rowptr[gid] = v;
        cursor[gid] = v;
    }
    if (gid == 0) rowptr[N] = E;
}

// ---------------- partitioned CSR placement ----------------
// 8 dst-range partitions; block p=blockIdx&7 only places dsts in its range, so its
// csr_src stores land in one contiguous ~E/8 slice (XCD-L2-local with the &7 swizzle).
__global__ void place_part_kernel(const void* __restrict__ edge, long long dstOff, int E,
                                  int* __restrict__ cursor, int* __restrict__ csr_src,
                                  const int* __restrict__ flags, int N) {
    const int part  = blockIdx.x & 7;
    const int chunk = blockIdx.x >> 3;
    const int lo = (int)((long long)N * part / 8);
    const int hi = (int)((long long)N * (part + 1) / 8);
    const int is64 = flags[0];
    int e = chunk * blockDim.x + threadIdx.x;
    if (e < E) {
        int d = getIdx(edge, dstOff + e, is64);
        if (d >= lo && d < hi) {
            int s = getIdx(edge, e, is64);
            int pos = atomicAdd(&cursor[d], 1);
            csr_src[pos] = s;
        }
    }
}

// ---------------- GEMM + dinv premultiply: out[r] = ((relu?)in[r] @ W) * dinv[r] ----------------
template <bool RELU, bool IN_IS_WS>
__global__ void gemm64_kernel(const void* __restrict__ in, const void* __restrict__ W,
                              const float* __restrict__ dinv, float* __restrict__ out,
                              int N, const int* __restrict__ flags) {
    const int isF32 = flags[1];
    const int lane = threadIdx.x & 63;
    float w[64];
#pragma unroll
    for (int k = 0; k < 64; ++k) w[k] = loadF(W, (size_t)k * 64 + lane, isF32);  // W[k][lane]
    const int wpb  = blockDim.x >> 6;
    int row = blockIdx.x * wpb + (threadIdx.x >> 6);
    const int stride = gridDim.x * wpb;
    for (; row < N; row += stride) {
        float xv;
        if (IN_IS_WS) xv = ((const float*)in)[(size_t)row * 64 + lane];
        else          xv = loadF(in, (size_t)row * 64 + lane, isF32);
        if (RELU) xv = fmaxf(xv, 0.0f);
        float acc = 0.0f;
#pragma unroll
        for (int k = 0; k < 64; ++k) {
            acc = fmaf(__shfl(xv, k, 64), w[k], acc);
        }
        out[(size_t)row * 64 + lane] = acc * dinv[row];
    }
}

// Common gather body: returns the aggregated xZ row element group (float4 per fi),
// valid in ALL lanes (slot-reduced). h' = h*dinv is pre-multiplied.
__device__ __forceinline__ float4 gather_row(const int* __restrict__ csr_src,
                                             const float4* __restrict__ h4,
                                             const float* __restrict__ dinv,
                                             const void* __restrict__ bias, int isF32,
                                             int i, int beg, int end, int slot, int fi) {
    float4 a0 = make_float4(0.f, 0.f, 0.f, 0.f);
    float4 a1 = make_float4(0.f, 0.f, 0.f, 0.f);
    float4 a2 = make_float4(0.f, 0.f, 0.f, 0.f);
    float4 a3 = make_float4(0.f, 0.f, 0.f, 0.f);
    int e = beg + slot;
    for (; e + 12 < end; e += 16) {
        int s0 = csr_src[e];
        int s1 = csr_src[e + 4];
        int s2 = csr_src[e + 8];
        int s3 = csr_src[e + 12];
        float4 v0 = h4[(size_t)s0 * 16 + fi];
        float4 v1 = h4[(size_t)s1 * 16 + fi];
        float4 v2 = h4[(size_t)s2 * 16 + fi];
        float4 v3 = h4[(size_t)s3 * 16 + fi];
        a0.x += v0.x; a0.y += v0.y; a0.z += v0.z; a0.w += v0.w;
        a1.x += v1.x; a1.y += v1.y; a1.z += v1.z; a1.w += v1.w;
        a2.x += v2.x; a2.y += v2.y; a2.z += v2.z; a2.w += v2.w;
        a3.x += v3.x; a3.y += v3.y; a3.z += v3.z; a3.w += v3.w;
    }
    for (; e < end; e += 4) {
        int s = csr_src[e];
        float4 v = h4[(size_t)s * 16 + fi];
        a0.x += v.x; a0.y += v.y; a0.z += v.z; a0.w += v.w;
    }
    a0.x += a1.x + a2.x + a3.x; a0.y += a1.y + a2.y + a3.y;
    a0.z += a1.z + a2.z + a3.z; a0.w += a1.w + a2.w + a3.w;
    a0.x += __shfl_xor(a0.x, 16, 64); a0.y += __shfl_xor(a0.y, 16, 64);
    a0.z += __shfl_xor(a0.z, 16, 64); a0.w += __shfl_xor(a0.w, 16, 64);
    a0.x += __shfl_xor(a0.x, 32, 64); a0.y += __shfl_xor(a0.y, 32, 64);
    a0.z += __shfl_xor(a0.z, 32, 64); a0.w += __shfl_xor(a0.w, 32, 64);
    const float di = dinv[i];
    float4 hi = h4[(size_t)i * 16 + fi];
    float4 r;
    r.x = fmaf(a0.x + hi.x, di, loadF(bias, fi * 4 + 0, isF32));
    r.y = fmaf(a0.y + hi.y, di, loadF(bias, fi * 4 + 1, isF32));
    r.z = fmaf(a0.z + hi.z, di, loadF(bias, fi * 4 + 2, isF32));
    r.w = fmaf(a0.w + hi.w, di, loadF(bias, fi * 4 + 3, isF32));
    return r;
}

// ---------------- layer-1 gather: writes the full row ----------------
__global__ void gather_kernel(const int* __restrict__ csr_src, const int* __restrict__ rowptr,
                              const float* __restrict__ dinv, const float* __restrict__ hp,
                              const void* __restrict__ bias, float* __restrict__ out,
                              int N, const int* __restrict__ flags) {
    const int isF32 = flags[1];
    const int lane = threadIdx.x & 63;
    const int slot = lane >> 4;
    const int fi   = lane & 15;
    int i = blockIdx.x * (blockDim.x >> 6) + (threadIdx.x >> 6);
    if (i >= N) return;
    float4 r = gather_row(csr_src, (const float4*)hp, dinv, bias, isF32,
                          i, rowptr[i], rowptr[i + 1], slot, fi);
    if (slot == 0) ((float4*)out)[(size_t)i * 16 + fi] = r;
}

// ---------------- layer-2 gather fused with heads ----------------
// mode 0: yi -> out[0:N], fprob -> out[N:2N], treat_prob -> out[3N:4N]
// mode 1: fprob_f -> out[2N:3N]
__global__ void gather_heads_kernel(const int* __restrict__ csr_src, const int* __restrict__ rowptr,
                                    const float* __restrict__ dinv, const float* __restrict__ hp,
                                    const void* __restrict__ bias,
                                    const void* __restrict__ Wy, const void* __restrict__ by,
                                    const void* __restrict__ Wp, const void* __restrict__ bp,
                                    const void* __restrict__ Wb, const void* __restrict__ bb,
                                    void* __restrict__ out, int N, int mode,
                                    const int* __restrict__ flags) {
    const int isF32 = flags[1];
    const int lane = threadIdx.x & 63;
    const int slot = lane >> 4;
    const int fi   = lane & 15;
    int i = blockIdx.x * (blockDim.x >> 6) + (threadIdx.x >> 6);
    if (i >= N) return;
    float4 r = gather_row(csr_src, (const float4*)hp, dinv, bias, isF32,
                          i, rowptr[i], rowptr[i + 1], slot, fi);
    if (mode == 0) {
        float py = r.x * loadF(Wy, fi * 4 + 0, isF32) + r.y * loadF(Wy, fi * 4 + 1, isF32)
                 + r.z * loadF(Wy, fi * 4 + 2, isF32) + r.w * loadF(Wy, fi * 4 + 3, isF32);
        float pp = r.x * loadF(Wp, fi * 4 + 0, isF32) + r.y * loadF(Wp, fi * 4 + 1, isF32)
                 + r.z * loadF(Wp, fi * 4 + 2, isF32) + r.w * loadF(Wp, fi * 4 + 3, isF32);
        float pb = r.x * loadF(Wb, fi * 4 + 0, isF32) + r.y * loadF(Wb, fi * 4 + 1, isF32)
                 + r.z * loadF(Wb, fi * 4 + 2, isF32) + r.w * loadF(Wb, fi * 4 + 3, isF32);
#pragma unroll
        for (int off = 8; off > 0; off >>= 1) {
            py += __shfl_xor(py, off, 64);
            pp += __shfl_xor(pp, off, 64);
            pb += __shfl_xor(pb, off, 64);
        }
        if (lane == 0) {
            storeF(out, (size_t)i,         fmaxf(py + loadF(by, 0, isF32), 0.0f), isF32);
            storeF(out, (size_t)N + i,     fmaxf(pp + loadF(bp, 0, isF32), 0.0f), isF32);
            storeF(out, (size_t)3 * N + i, fmaxf(pb + loadF(bb, 0, isF32), 0.0f), isF32);
        }
    } else {
        float pp = r.x * loadF(Wp, fi * 4 + 0, isF32) + r.y * loadF(Wp, fi * 4 + 1, isF32)
                 + r.z * loadF(Wp, fi * 4 + 2, isF32) + r.w * loadF(Wp, fi * 4 + 3, isF32);
#pragma unroll
        for (int off = 8; off > 0; off >>= 1) pp += __shfl_xor(pp, off, 64);
        if (lane == 0)
            storeF(out, (size_t)2 * N + i, fmaxf(pp + loadF(bp, 0, isF32), 0.0f), isF32);
    }
}

extern "C" void kernel_launch(void* const* d_in, const int* in_sizes, int n_in,
                              void* d_out, int out_size, void* d_ws, size_t ws_size,
                              hipStream_t stream) {
    const void* x   = d_in[0];
    const void* ei  = d_in[1];
    const void* fx  = d_in[2];
    const void* fei = d_in[3];
    const void* W1  = d_in[4];
    const void* b1  = d_in[5];
    const void* W2  = d_in[6];
    const void* b2  = d_in[7];
    const void* Wy  = d_in[8];
    const void* by  = d_in[9];
    const void* Wp  = d_in[10];
    const void* bp  = d_in[11];
    const void* Wb  = d_in[12];
    const void* bb  = d_in[13];

    const int N = in_sizes[0] / 64;
    const int E = in_sizes[1] / 2;

    // ws layout (ints first, then floats):
    // flags[16] | deg[N] | rowptr[N+1] | cursor[N] | blockSums[1024] | csr_src[E]
    // | dinv[N] f32 | bufA[N*64] f32 (16B aligned) | bufB[N*64] f32
    int*   flags     = (int*)d_ws;
    int*   deg       = flags + 16;
    int*   rowptr    = deg + N;
    int*   cursor    = rowptr + (N + 1);
    int*   blockSums = cursor + N;
    int*   csr_src   = blockSums + 1024;
    float* dinv      = (float*)(csr_src + E);
    size_t off = ((size_t)(dinv + N) + 15) & ~(size_t)15;
    float* bufA      = (float*)off;
    float* bufB      = bufA + (size_t)N * 64;

    const int THREADS = 256;
    const int nbN = (N + 255) / 256;
    const int nbE = (E + THREADS - 1) / THREADS;

    detect_kernel<<<1, 64, 0, stream>>>(ei, x, flags);

    for (int g = 0; g < 2; ++g) {
        const void* xg   = g ? fx : x;
        const void* edge = g ? fei : ei;
        const long long dstOff = E;

        // ---- CSR build (shared by both layers) ----
        hipMemsetAsync(deg, 0, (size_t)N * sizeof(int), stream);
        degree_kernel<<<nbE, THREADS, 0, stream>>>(edge, dstOff, E, deg, flags);
        dinv_kernel<<<nbN, 256, 0, stream>>>(deg, dinv, N);
        scan1_kernel<<<nbN, 256, 0, stream>>>(deg, rowptr, blockSums, N);
        scan2_kernel<<<1, 512, 0, stream>>>(blockSums, nbN);
        scan3_kernel<<<nbN, 256, 0, stream>>>(rowptr, blockSums, cursor, N, E);
        place_part_kernel<<<nbE * 8, THREADS, 0, stream>>>(edge, dstOff, E, cursor, csr_src, flags, N);

        // ---- layer 1 ----
        gemm64_kernel<false, false><<<2048, THREADS, 0, stream>>>(xg, W1, dinv, bufA, N, flags);
        gather_kernel<<<(N + 3) / 4, THREADS, 0, stream>>>(csr_src, rowptr, dinv, bufA, b1, bufB, N, flags);

        // ---- layer 2 + heads (relu fused into GEMM load) ----
        gemm64_kernel<true, true><<<2048, THREADS, 0, stream>>>(bufB, W2, dinv, bufA, N, flags);
        gather_heads_kernel<<<(N + 3) / 4, THREADS, 0, stream>>>(csr_src, rowptr, dinv, bufA, b2,
                                                                 Wy, by, Wp, bp, Wb, bb, d_out, N, g, flags);
    }
}

// Round 7
// 965.799 us; speedup vs baseline: 2.0535x; 1.1512x over previous
//
#include <hip/hip_runtime.h>
#include <hip/hip_bf16.h>

typedef __hip_bfloat16 bf16;

__device__ __forceinline__ float b2f(bf16 v) { return __bfloat162float(v); }

// flags[0] = 1 if edge_index is int64, 0 if int32
// flags[1] = 1 if float tensors (and output) are fp32, 0 if bf16
__global__ void detect_kernel(const void* __restrict__ edge, const void* __restrict__ x,
                              int* __restrict__ flags) {
    if (blockIdx.x != 0 || threadIdx.x != 0) return;
    const int* e32 = (const int*)edge;
    int allzero = 1;
    for (int k = 1; k < 1024; k += 2)       if (e32[k] != 0) { allzero = 0; break; }
    if (allzero)
        for (int k = 1000001; k < 1002048; k += 2) if (e32[k] != 0) { allzero = 0; break; }
    flags[0] = allzero;
    const unsigned short* u = (const unsigned short*)x;
    int insane = 0;
    for (int k = 0; k < 512; k += 2) {
        int ex = (u[k] >> 7) & 0xFF;
        if (ex != 0 && (ex < 90 || ex > 160)) insane++;
    }
    flags[1] = (insane > 64) ? 1 : 0;
}

__device__ __forceinline__ int getIdx(const void* p, long long i, int is64) {
    return is64 ? (int)(((const long long*)p)[i]) : ((const int*)p)[i];
}
__device__ __forceinline__ float loadF(const void* p, size_t i, int isF32) {
    return isF32 ? ((const float*)p)[i] : b2f(((const bf16*)p)[i]);
}
__device__ __forceinline__ void storeF(void* p, size_t i, float v, int isF32) {
    if (isF32) ((float*)p)[i] = v;
    else       ((bf16*)p)[i]  = __float2bfloat16(v);
}

// ---------------- head constants: c[k] = b2 @ W_head[k] + b_head[k] ----------------
__global__ void constk_kernel(const void* __restrict__ b2,
                              const void* __restrict__ Wy, const void* __restrict__ by,
                              const void* __restrict__ Wp, const void* __restrict__ bp,
                              const void* __restrict__ Wb, const void* __restrict__ bb,
                              float* __restrict__ c, const int* __restrict__ flags) {
    const int isF32 = flags[1];
    const int lane = threadIdx.x & 63;
    float b = loadF(b2, lane, isF32);
    float cy = b * loadF(Wy, lane, isF32);
    float cp = b * loadF(Wp, lane, isF32);
    float cb = b * loadF(Wb, lane, isF32);
#pragma unroll
    for (int off = 32; off > 0; off >>= 1) {
        cy += __shfl_xor(cy, off, 64);
        cp += __shfl_xor(cp, off, 64);
        cb += __shfl_xor(cb, off, 64);
    }
    if (lane == 0) {
        c[0] = cy + loadF(by, 0, isF32);
        c[1] = cp + loadF(bp, 0, isF32);
        c[2] = cb + loadF(bb, 0, isF32);
    }
}

// ---------------- partitioned degree histogram ----------------
__global__ void degree_part_kernel(const void* __restrict__ edge, long long dstOff, int E,
                                   int* __restrict__ deg, const int* __restrict__ flags, int N) {
    const int part  = blockIdx.x & 7;
    const int chunk = blockIdx.x >> 3;
    const int lo = (int)((long long)N * part / 8);
    const int hi = (int)((long long)N * (part + 1) / 8);
    int e = chunk * blockDim.x + threadIdx.x;
    if (e < E) {
        int d = getIdx(edge, dstOff + e, flags[0]);
        if (d >= lo && d < hi) atomicAdd(&deg[d], 1);
    }
}

__global__ void dinv_kernel(const int* __restrict__ deg, float* __restrict__ dinv, int N) {
    int i = blockIdx.x * blockDim.x + threadIdx.x;
    if (i < N) dinv[i] = rsqrtf((float)deg[i] + 1.0f);   // +1 self-loop
}

// ---------------- exclusive scan of deg -> rowptr (3 kernels) ----------------
__global__ void scan1_kernel(const int* __restrict__ deg, int* __restrict__ rowptr,
                             int* __restrict__ blockSums, int N) {
    __shared__ int tmp[256];
    int gid = blockIdx.x * 256 + threadIdx.x;
    int v = (gid < N) ? deg[gid] : 0;
    tmp[threadIdx.x] = v;
    __syncthreads();
#pragma unroll
    for (int off = 1; off < 256; off <<= 1) {
        int t = (threadIdx.x >= off) ? tmp[threadIdx.x - off] : 0;
        __syncthreads();
        tmp[threadIdx.x] += t;
        __syncthreads();
    }
    if (gid < N) rowptr[gid] = tmp[threadIdx.x] - v;
    if (threadIdx.x == 255) blockSums[blockIdx.x] = tmp[255];
}

__global__ void scan2_kernel(int* __restrict__ blockSums, int nb) {
    __shared__ int tmp[512];
    int v = (threadIdx.x < nb) ? blockSums[threadIdx.x] : 0;
    tmp[threadIdx.x] = v;
    __syncthreads();
#pragma unroll
    for (int off = 1; off < 512; off <<= 1) {
        int t = (threadIdx.x >= off) ? tmp[threadIdx.x - off] : 0;
        __syncthreads();
        tmp[threadIdx.x] += t;
        __syncthreads();
    }
    if (threadIdx.x < nb) blockSums[threadIdx.x] = tmp[threadIdx.x] - v;
}

__global__ void scan3_kernel(int* __restrict__ rowptr, const int* __restrict__ blockSums,
                             int* __restrict__ cursor, int N, int E) {
    int gid = blockIdx.x * 256 + threadIdx.x;
    if (gid < N) {
        int v = rowptr[gid] + blockSums[blockIdx.x];
        rowptr[gid] = v;
        cursor[gid] = v;
    }
    if (gid == 0) rowptr[N] = E;
}

// ---------------- partitioned CSR placement ----------------
__global__ void place_part_kernel(const void* __restrict__ edge, long long dstOff, int E,
                                  int* __restrict__ cursor, int* __restrict__ csr_src,
                                  const int* __restrict__ flags, int N) {
    const int part  = blockIdx.x & 7;
    const int chunk = blockIdx.x >> 3;
    const int lo = (int)((long long)N * part / 8);
    const int hi = (int)((long long)N * (part + 1) / 8);
    const int is64 = flags[0];
    int e = chunk * blockDim.x + threadIdx.x;
    if (e < E) {
        int d = getIdx(edge, dstOff + e, is64);
        if (d >= lo && d < hi) {
            int s = getIdx(edge, e, is64);
            int pos = atomicAdd(&cursor[d], 1);
            csr_src[pos] = s;
        }
    }
}

// ---------------- layer-1 GEMM + dinv premultiply: out[r] = (in[r] @ W) * dinv[r] ----------------
__global__ void gemm64_kernel(const void* __restrict__ in, const void* __restrict__ W,
                              const float* __restrict__ dinv, float* __restrict__ out,
                              int N, const int* __restrict__ flags) {
    const int isF32 = flags[1];
    const int lane = threadIdx.x & 63;
    float w[64];
#pragma unroll
    for (int k = 0; k < 64; ++k) w[k] = loadF(W, (size_t)k * 64 + lane, isF32);  // W[k][lane]
    const int wpb  = blockDim.x >> 6;
    int row = blockIdx.x * wpb + (threadIdx.x >> 6);
    const int stride = gridDim.x * wpb;
    for (; row < N; row += stride) {
        float xv = loadF(in, (size_t)row * 64 + lane, isF32);
        float acc = 0.0f;
#pragma unroll
        for (int k = 0; k < 64; ++k) {
            acc = fmaf(__shfl(xv, k, 64), w[k], acc);
        }
        out[(size_t)row * 64 + lane] = acc * dinv[row];
    }
}

// ---------------- layer-2 GEMM fused with head projections ----------------
// t4[r] = {h2'(r)@Wy, h2'(r)@Wp, h2'(r)@Wb, 0},  h2'(r) = (relu(xZ1[r]) @ W2) * dinv[r]
__global__ void gemm64_heads_kernel(const float* __restrict__ in, const void* __restrict__ W,
                                    const float* __restrict__ dinv,
                                    const void* __restrict__ Wy, const void* __restrict__ Wp,
                                    const void* __restrict__ Wb,
                                    float4* __restrict__ t4, int N, const int* __restrict__ flags) {
    const int isF32 = flags[1];
    const int lane = threadIdx.x & 63;
    float w[64];
#pragma unroll
    for (int k = 0; k < 64; ++k) w[k] = loadF(W, (size_t)k * 64 + lane, isF32);
    const float wy = loadF(Wy, lane, isF32);
    const float wp = loadF(Wp, lane, isF32);
    const float wb = loadF(Wb, lane, isF32);
    const int wpb  = blockDim.x >> 6;
    int row = blockIdx.x * wpb + (threadIdx.x >> 6);
    const int stride = gridDim.x * wpb;
    for (; row < N; row += stride) {
        float xv = fmaxf(in[(size_t)row * 64 + lane], 0.0f);
        float acc = 0.0f;
#pragma unroll
        for (int k = 0; k < 64; ++k) {
            acc = fmaf(__shfl(xv, k, 64), w[k], acc);
        }
        float h  = acc * dinv[row];
        float ty = h * wy, tp = h * wp, tb = h * wb;
#pragma unroll
        for (int off = 32; off > 0; off >>= 1) {
            ty += __shfl_xor(ty, off, 64);
            tp += __shfl_xor(tp, off, 64);
            tb += __shfl_xor(tb, off, 64);
        }
        if (lane == 0) t4[row] = make_float4(ty, tp, tb, 0.0f);
    }
}

// ---------------- layer-1 gather: full 64-dim row ----------------
__global__ void gather_kernel(const int* __restrict__ csr_src, const int* __restrict__ rowptr,
                              const float* __restrict__ dinv, const float* __restrict__ hp,
                              const void* __restrict__ bias, float* __restrict__ out,
                              int N, const int* __restrict__ flags) {
    const int isF32 = flags[1];
    const int lane = threadIdx.x & 63;
    const int slot = lane >> 4;
    const int fi   = lane & 15;
    int i = blockIdx.x * (blockDim.x >> 6) + (threadIdx.x >> 6);
    if (i >= N) return;
    const int beg = rowptr[i];
    const int end = rowptr[i + 1];
    const float4* __restrict__ h4 = (const float4*)hp;

    float4 a0 = make_float4(0.f, 0.f, 0.f, 0.f);
    float4 a1 = make_float4(0.f, 0.f, 0.f, 0.f);
    float4 a2 = make_float4(0.f, 0.f, 0.f, 0.f);
    float4 a3 = make_float4(0.f, 0.f, 0.f, 0.f);
    int e = beg + slot;
    for (; e + 12 < end; e += 16) {
        int s0 = csr_src[e];
        int s1 = csr_src[e + 4];
        int s2 = csr_src[e + 8];
        int s3 = csr_src[e + 12];
        float4 v0 = h4[(size_t)s0 * 16 + fi];
        float4 v1 = h4[(size_t)s1 * 16 + fi];
        float4 v2 = h4[(size_t)s2 * 16 + fi];
        float4 v3 = h4[(size_t)s3 * 16 + fi];
        a0.x += v0.x; a0.y += v0.y; a0.z += v0.z; a0.w += v0.w;
        a1.x += v1.x; a1.y += v1.y; a1.z += v1.z; a1.w += v1.w;
        a2.x += v2.x; a2.y += v2.y; a2.z += v2.z; a2.w += v2.w;
        a3.x += v3.x; a3.y += v3.y; a3.z += v3.z; a3.w += v3.w;
    }
    for (; e < end; e += 4) {
        int s = csr_src[e];
        float4 v = h4[(size_t)s * 16 + fi];
        a0.x += v.x; a0.y += v.y; a0.z += v.z; a0.w += v.w;
    }
    a0.x += a1.x + a2.x + a3.x; a0.y += a1.y + a2.y + a3.y;
    a0.z += a1.z + a2.z + a3.z; a0.w += a1.w + a2.w + a3.w;
    a0.x += __shfl_xor(a0.x, 16, 64); a0.y += __shfl_xor(a0.y, 16, 64);
    a0.z += __shfl_xor(a0.z, 16, 64); a0.w += __shfl_xor(a0.w, 16, 64);
    a0.x += __shfl_xor(a0.x, 32, 64); a0.y += __shfl_xor(a0.y, 32, 64);
    a0.z += __shfl_xor(a0.z, 32, 64); a0.w += __shfl_xor(a0.w, 32, 64);

    if (slot == 0) {
        const float di = dinv[i];
        float4 hi = h4[(size_t)i * 16 + fi];
        float4 r;
        r.x = fmaf(a0.x + hi.x, di, loadF(bias, fi * 4 + 0, isF32));
        r.y = fmaf(a0.y + hi.y, di, loadF(bias, fi * 4 + 1, isF32));
        r.z = fmaf(a0.z + hi.z, di, loadF(bias, fi * 4 + 2, isF32));
        r.w = fmaf(a0.w + hi.w, di, loadF(bias, fi * 4 + 3, isF32));
        ((float4*)out)[(size_t)i * 16 + fi] = r;
    }
}

// ---------------- layer-2 scalar gather + heads ----------------
// 4 lanes per node; t4 is 1.6 MB (L2-resident).
// mode 0: yi -> out[0:N], fprob -> out[N:2N], treat_prob -> out[3N:4N]
// mode 1: fprob_f -> out[2N:3N]
__global__ void gather_scalar_kernel(const int* __restrict__ csr_src, const int* __restrict__ rowptr,
                                     const float* __restrict__ dinv, const float4* __restrict__ t4,
                                     const float* __restrict__ c, void* __restrict__ out,
                                     int N, int mode, const int* __restrict__ flags) {
    int tid  = blockIdx.x * blockDim.x + threadIdx.x;
    int i    = tid >> 2;
    int slot = tid & 3;
    if (i >= N) return;
    const int beg = rowptr[i];
    const int end = rowptr[i + 1];
    float ax = 0.f, ay = 0.f, az = 0.f;
    for (int e = beg + slot; e < end; e += 4) {
        float4 t = t4[csr_src[e]];
        ax += t.x; ay += t.y; az += t.z;
    }
    ax += __shfl_xor(ax, 1, 64); ay += __shfl_xor(ay, 1, 64); az += __shfl_xor(az, 1, 64);
    ax += __shfl_xor(ax, 2, 64); ay += __shfl_xor(ay, 2, 64); az += __shfl_xor(az, 2, 64);
    if (slot == 0) {
        const int isF32 = flags[1];
        float4 ti = t4[i];
        float di  = dinv[i];
        if (mode == 0) {
            storeF(out, (size_t)i,         fmaxf(fmaf(di, ax + ti.x, c[0]), 0.0f), isF32);
            storeF(out, (size_t)N + i,     fmaxf(fmaf(di, ay + ti.y, c[1]), 0.0f), isF32);
            storeF(out, (size_t)3 * N + i, fmaxf(fmaf(di, az + ti.z, c[2]), 0.0f), isF32);
        } else {
            storeF(out, (size_t)2 * N + i, fmaxf(fmaf(di, ay + ti.y, c[1]), 0.0f), isF32);
        }
    }
}

extern "C" void kernel_launch(void* const* d_in, const int* in_sizes, int n_in,
                              void* d_out, int out_size, void* d_ws, size_t ws_size,
                              hipStream_t stream) {
    const void* x   = d_in[0];
    const void* ei  = d_in[1];
    const void* fx  = d_in[2];
    const void* fei = d_in[3];
    const void* W1  = d_in[4];
    const void* b1  = d_in[5];
    const void* W2  = d_in[6];
    const void* b2  = d_in[7];
    const void* Wy  = d_in[8];
    const void* by  = d_in[9];
    const void* Wp  = d_in[10];
    const void* bp  = d_in[11];
    const void* Wb  = d_in[12];
    const void* bb  = d_in[13];

    const int N = in_sizes[0] / 64;
    const int E = in_sizes[1] / 2;

    // ws layout (ints first, then floats):
    // flags[16] | deg[N] | rowptr[N+1] | cursor[N] | blockSums[1024] | csr_src[E]
    // | dinv[N] f32 | cvals[16] f32 | bufA[N*64] f32 (16B aligned) | bufB[N*64] f32 | t4[N] float4
    int*   flags     = (int*)d_ws;
    int*   deg       = flags + 16;
    int*   rowptr    = deg + N;
    int*   cursor    = rowptr + (N + 1);
    int*   blockSums = cursor + N;
    int*   csr_src   = blockSums + 1024;
    float* dinv      = (float*)(csr_src + E);
    float* cvals     = dinv + N;
    size_t off = ((size_t)(cvals + 16) + 15) & ~(size_t)15;
    float* bufA      = (float*)off;
    float* bufB      = bufA + (size_t)N * 64;
    float4* t4       = (float4*)(bufB + (size_t)N * 64);

    const int THREADS = 256;
    const int nbN = (N + 255) / 256;
    const int nbE = (E + THREADS - 1) / THREADS;

    detect_kernel<<<1, 64, 0, stream>>>(ei, x, flags);
    constk_kernel<<<1, 64, 0, stream>>>(b2, Wy, by, Wp, bp, Wb, bb, cvals, flags);

    for (int g = 0; g < 2; ++g) {
        const void* xg   = g ? fx : x;
        const void* edge = g ? fei : ei;
        const long long dstOff = E;

        // ---- CSR build (shared by both layers) ----
        hipMemsetAsync(deg, 0, (size_t)N * sizeof(int), stream);
        degree_part_kernel<<<nbE * 8, THREADS, 0, stream>>>(edge, dstOff, E, deg, flags, N);
        dinv_kernel<<<nbN, 256, 0, stream>>>(deg, dinv, N);
        scan1_kernel<<<nbN, 256, 0, stream>>>(deg, rowptr, blockSums, N);
        scan2_kernel<<<1, 512, 0, stream>>>(blockSums, nbN);
        scan3_kernel<<<nbN, 256, 0, stream>>>(rowptr, blockSums, cursor, N, E);
        place_part_kernel<<<nbE * 8, THREADS, 0, stream>>>(edge, dstOff, E, cursor, csr_src, flags, N);

        // ---- layer 1 ----
        gemm64_kernel<<<2048, THREADS, 0, stream>>>(xg, W1, dinv, bufA, N, flags);
        gather_kernel<<<(N + 3) / 4, THREADS, 0, stream>>>(csr_src, rowptr, dinv, bufA, b1, bufB, N, flags);

        // ---- layer 2: GEMM + head projection to per-node scalars, then scalar gather ----
        gemm64_heads_kernel<<<2048, THREADS, 0, stream>>>(bufB, W2, dinv, Wy, Wp, Wb, t4, N, flags);
        gather_scalar_kernel<<<(4 * N + THREADS - 1) / THREADS, THREADS, 0, stream>>>(
            csr_src, rowptr, dinv, t4, cvals, d_out, N, g, flags);
    }
}